// Round 3
// baseline (192.000 us; speedup 1.0000x reference)
//
#include <hip/hip_runtime.h>
#include <hip/hip_bf16.h>

// Problem constants (fixed by setup_inputs): B=4, N=16384, M=128, C=128, S=512.
// Output layout (float32): pooled (B*M*S*(C+3)) then empty_flag (B*M) as 0.0/1.0.
#define BB   4
#define NN   16384
#define MM   128
#define CC   128
#define SS   512
#define CH   (CC + 3)      // 131
#define BM   (BB * MM)     // 512
#define WAVES 8            // waves per box in kernel A
#define CHUNK (NN / WAVES) // 2048 points per wave

// Session lessons (keep):
//  R5: fusing A+B into one kernel loses 8x gather TLP -> +20us. Don't.
//  R6: nontemporal output stores -> +7us. Don't.
//  R7: vectorizing A's point loads was neutral -> A is not VMEM-issue-bound.
//  R8: naive row-major LDS staging in B had 4-8 way bank conflicts.
//  R9: swizzled-LDS staging + dense dwordx4 stores: 195.4->191.9us.
//      => B is NOT store-transaction-bound.
//  R10: XCD-affinity remap of B's grid: 191.9->191.0us, NEUTRAL.
//      => B is NOT L2-locality/cache-BW-bound. (Kept: free, bijective.)
//  R11 evidence: our kernels never enter rocprof top-5 (each <=~81.5us) yet
//      dur_us=191 => timed window includes harness re-poison fills
//      (536584 KB = exactly 4x the 137.4 MB output buffer, ~83us each).
//      Controllable A+B is ~25..108us. R5/R6 say B is gather-LATENCY/
//      issue-bound, so this round cuts B's dependent-load chain:
//      A's epilogue writes {idx,x,y,z} float4 records (points re-gathered
//      from the L2-hot 196KB table); B loads 4 broadcast records/thread
//      (k=4hw+s, consecutive) and gathers only features.
//      B: 12 load instrs -> 8, scattered 3-of-32-lane point gather gone,
//      xyz moves from hop 2 to hop 1.
#define SWZ(d) ((d) ^ (((d) >> 5) & 31))

// ---------------------------------------------------------------------------
// Kernel A: one block (8 waves, 512 thr) per box.
// Each lane owns 4 consecutive points (48 B = 3 aligned float4 loads).
// Stable compaction: group point order is (lane t major, u minor) = 4t+u, so
// pos = cnt + sum_u' popcll(M[u'] & lower(t)) + popc(m & ((1<<u)-1)).
// Waves merge by prefix offsets (stable), wrap-fill idx[k]=idx[k%cnt].
// Rotation test in double (true value >> fp32 ref roundoff); z-test fp32
// bit-identical to numpy.
// Epilogue (R11): re-gather sampled coords and emit {idx,x,y,z} records.
// ---------------------------------------------------------------------------
__global__ __launch_bounds__(512)
void box_sample_kernel(const float* __restrict__ points,  // (B,N,3)
                       const float* __restrict__ boxes,   // (B,M,7)
                       float4* __restrict__ rec_ws,       // (BM,SS) {idx,x,y,z}
                       int*  __restrict__ cnt_ws,         // (BM)
                       float* __restrict__ flag_out)      // (BM)
{
    const int box  = blockIdx.x;          // b*MM + m
    const int b    = box >> 7;            // MM = 128
    const int lane = threadIdx.x & 63;
    const int w    = threadIdx.x >> 6;    // wave 0..7

    const float4* P4 = (const float4*)(points + (size_t)b * NN * 3);
    const float*  bx = boxes + (size_t)box * 7;

    const float cx = bx[0], cy = bx[1], cz = bx[2];
    const float dx = bx[3], dy = bx[4], dz = bx[5], rz = bx[6];

    const float  czc = cz + dz * 0.5f;     // exact
    const float  hz  = dz * 0.5f;          // exact
    const double ca  = cos(-(double)rz);
    const double sa  = sin(-(double)rz);
    const double hx  = (double)dx * 0.5;
    const double hy  = (double)dy * 0.5;

    __shared__ int s_part[WAVES][SS];     // 16 KB
    __shared__ int s_cnt[WAVES];
    __shared__ int s_idx[SS];

    int cnt = 0;
    const int pbase = w * CHUNK;
    for (int i0 = 0; i0 < CHUNK; i0 += 256) {     // 8 outer iterations
        const int pt0 = pbase + i0 + 4 * lane;    // first of this lane's 4 points
        const int f4b = (pt0 * 3) >> 2;           // pt0 % 4 == 0 -> exact
        const float4 q0 = P4[f4b + 0];   // p0.x p0.y p0.z p1.x
        const float4 q1 = P4[f4b + 1];   // p1.y p1.z p2.x p2.y
        const float4 q2 = P4[f4b + 2];   // p2.z p3.x p3.y p3.z
        const float px[4] = {q0.x, q0.w, q1.z, q2.y};
        const float py[4] = {q0.y, q1.x, q1.w, q2.z};
        const float pz[4] = {q0.z, q1.y, q2.x, q2.w};

        unsigned m = 0;
        #pragma unroll
        for (int u = 0; u < 4; ++u) {
            const double sx = (double)px[u] - (double)cx;
            const double sy = (double)py[u] - (double)cy;
            const float  szf = pz[u] - czc;
            const double lx = sx * ca - sy * sa;
            const double ly = sx * sa + sy * ca;
            const bool inside = (fabs(lx) < hx) && (fabs(ly) < hy) && (fabsf(szf) <= hz);
            m |= (unsigned)inside << u;
        }

        unsigned long long M[4];
        #pragma unroll
        for (int u = 0; u < 4; ++u) M[u] = __ballot((m >> u) & 1u);

        const unsigned long long lower = (1ull << lane) - 1ull;
        int lanebase = cnt;
        #pragma unroll
        for (int u = 0; u < 4; ++u) lanebase += __popcll(M[u] & lower);

        #pragma unroll
        for (int u = 0; u < 4; ++u) {
            if ((m >> u) & 1u) {
                const int pos = lanebase + __builtin_popcount(m & ((1u << u) - 1u));
                if (pos < SS) s_part[w][pos] = pt0 + u;
            }
        }
        #pragma unroll
        for (int u = 0; u < 4; ++u) cnt += __popcll(M[u]);
    }
    if (lane == 0) s_cnt[w] = cnt;
    __syncthreads();

    int c[WAVES], off[WAVES];
    int total = 0;
    #pragma unroll
    for (int q = 0; q < WAVES; ++q) { c[q] = s_cnt[q]; off[q] = total; total += c[q]; }

    // merge segments into first min(total,SS) slots, stable order
    for (int k = threadIdx.x; k < SS; k += 512) {
        int v = 0;
        #pragma unroll
        for (int q = 0; q < WAVES; ++q) {
            const int r = k - off[q];
            if (r >= 0 && r < c[q]) v = s_part[q][r];
        }
        s_idx[k] = v;
    }
    __syncthreads();

    if (total > 0 && total < SS) {
        for (int k = total + threadIdx.x; k < SS; k += 512)
            s_idx[k] = s_idx[k % total];
        __syncthreads();
    }

    // R11 epilogue: emit {idx, x, y, z} records. Point table (196 KB/batch)
    // is L2-hot from the scan; scattered dword loads are cheap here and save
    // B a dependent scattered gather.
    float4* dst = rec_ws + (size_t)box * SS;
    const float* Pb = points + (size_t)b * NN * 3;
    for (int k = threadIdx.x; k < SS; k += 512) {
        const int id = s_idx[k];
        float4 r;
        r.x = __int_as_float(id);
        r.y = Pb[id * 3 + 0];
        r.z = Pb[id * 3 + 1];
        r.w = Pb[id * 3 + 2];
        dst[k] = r;
    }
    if (threadIdx.x == 0) {
        cnt_ws[box]   = total;
        flag_out[box] = (total == 0) ? 1.0f : 0.0f;
    }
}

// ---------------------------------------------------------------------------
// Kernel B: record-driven gather with swizzled-LDS staging -> dense aligned
// float4 stores. Grid: 8192 flat workgroups, XCD-affinity remapped (R10).
// 256 threads = 8 half-waves; half-wave hw owns samples k = 4*hw + s
// (s=0..3): 4 consecutive broadcast float4 record loads per thread, then 4
// independent float4 feature gathers (max MLP per R5), SWZ'd LDS staging
// (R9), dense aligned dwordx4 over the chunk's contiguous 16768-B span.
// ---------------------------------------------------------------------------
__global__ __launch_bounds__(256)
void gather_kernel(const float4* __restrict__ rec_ws,  // (BM,SS) {idx,x,y,z}
                   const float* __restrict__ feats,    // (B,N,C)
                   const int*   __restrict__ cnt_ws,   // (BM)
                   float* __restrict__ out)            // (BM,SS,CH)
{
    // R10 XCD-affinity decode: flat id -> (batch, m, chunk) such that batch b
    // lands only on XCDs {2b, 2b+1} under HW round-robin (XCD = flat % 8).
    const int flat  = blockIdx.x;
    const int r     = flat & 7;
    const int b     = r >> 1;
    const int s2    = ((flat >> 3) << 1) | (r & 1);
    const int m     = s2 & (MM - 1);
    const int chunk = s2 >> 7;            // 0..15
    const int box   = (b << 7) + m;

    const int tid   = threadIdx.x;
    const int hw    = tid >> 5;           // half-wave 0..7
    const int j     = tid & 31;           // lane in half-wave

    __shared__ float s_out[32 * CH];      // 4192 dwords = 16768 B

    const float scale = (cnt_ws[box] > 0) ? 1.0f : 0.0f;
    const float4* recp = rec_ws + (size_t)box * SS + chunk * 32;

    float4 rec[4];
    #pragma unroll
    for (int s = 0; s < 4; ++s) rec[s] = recp[4 * hw + s];   // broadcast loads

    const float4* F4 = (const float4*)(feats + (size_t)b * NN * CC);

    float4 v[4];
    #pragma unroll
    for (int s = 0; s < 4; ++s) v[s] = F4[__float_as_int(rec[s].x) * 32 + j];

    // Swizzled staging. Row k = 4*hw+s owns dwords [k*131, k*131+131).
    #pragma unroll
    for (int s = 0; s < 4; ++s) {
        const int k    = 4 * hw + s;
        const int base = k * CH + 3 + 4 * j;
        s_out[SWZ(base + 0)] = v[s].x * scale;
        s_out[SWZ(base + 1)] = v[s].y * scale;
        s_out[SWZ(base + 2)] = v[s].z * scale;
        s_out[SWZ(base + 3)] = v[s].w * scale;
        if (j < 3) {
            const float p = (j == 0) ? rec[s].y : ((j == 1) ? rec[s].z : rec[s].w);
            s_out[SWZ(k * CH + j)] = p * scale;
        }
    }
    __syncthreads();

    // Dense aligned output. Chunk span start = 16768 B * (16*box+chunk),
    // 16B-aligned; 1048 float4s covered by 256 threads.
    float* dst = out + (size_t)box * SS * CH + (size_t)chunk * 32 * CH;
    for (int t = tid; t < (32 * CH) / 4; t += 256) {
        const int dw = 4 * t;
        float4 o;
        o.x = s_out[SWZ(dw + 0)];
        o.y = s_out[SWZ(dw + 1)];
        o.z = s_out[SWZ(dw + 2)];
        o.w = s_out[SWZ(dw + 3)];
        ((float4*)dst)[t] = o;
    }
}

extern "C" void kernel_launch(void* const* d_in, const int* in_sizes, int n_in,
                              void* d_out, int out_size, void* d_ws, size_t ws_size,
                              hipStream_t stream) {
    const float* points = (const float*)d_in[0];
    const float* feats  = (const float*)d_in[1];
    const float* boxes  = (const float*)d_in[2];
    // d_in[3] = num_sampled_points, fixed at 512 by setup_inputs.

    float4* rec_ws = (float4*)d_ws;                  // BM*SS float4 = 4 MiB
    int*    cnt_ws = (int*)(rec_ws + (size_t)BM * SS); // BM ints
    float*  out      = (float*)d_out;
    float*  flag_out = out + (size_t)BM * SS * CH;   // empty_flag as float 0/1

    box_sample_kernel<<<BM, 512, 0, stream>>>(points, boxes, rec_ws, cnt_ws, flag_out);
    gather_kernel<<<BM * (SS / 32), 256, 0, stream>>>(rec_ws, feats, cnt_ws, out);
}